// Round 2
// baseline (1215.192 us; speedup 1.0000x reference)
//
#include <hip/hip_runtime.h>

// ShallowSIRENWithPosEmb: fused 3-layer FiLM-SIREN, fp32 VALU version.
// B=4, N=65536, H=256. 64 points per block, 256 threads (4 waves).
// Weights pre-transposed into d_ws ([k][o] layout) by a small kernel so the
// GEMM k-loop does dense 16B-per-lane global loads (L1/L2 broadcast).

#define SCALE_F 8.333333333333334f   // 2/0.24

// d_ws float offsets
#define OFF_W1T   0                   // [63][256]
#define OFF_W2T   16384               // [256][256]
#define OFF_WCST  (16384 + 65536)     // [283][256] (rows 0..26 = dir-embed, 27..282 = x)

// ---------------- accurate sin/cos via Cody-Waite reduction to revolutions ----
__device__ __forceinline__ float redrev(float x) {
  const float chi = 0.15915494309189535f;   // fp32(1/2pi)
  const float clo = 6.4206383e-09f;         // 1/2pi - (double)chi
  float n = rintf(x * chi);
  float d = __builtin_fmaf(x, chi, -n);     // single-rounding cancellation
  return __builtin_fmaf(x, clo, d);         // |result| <= ~0.5 revolutions
}
__device__ __forceinline__ float fsin(float x) { return __builtin_amdgcn_sinf(redrev(x)); }
__device__ __forceinline__ float fcos(float x) { return __builtin_amdgcn_cosf(redrev(x)); }

// ---------------- register-tile helpers (functions, not macros!) ----------------
__device__ __forceinline__ void fmaq(float* a, float s, float4 xv) {
  a[0] = __builtin_fmaf(s, xv.x, a[0]); a[1] = __builtin_fmaf(s, xv.y, a[1]);
  a[2] = __builtin_fmaf(s, xv.z, a[2]); a[3] = __builtin_fmaf(s, xv.w, a[3]);
}
__device__ __forceinline__ void fmag(float* a, float4 wv, float4 xv) {
  fmaq(a + 0, wv.x, xv); fmaq(a + 4, wv.y, xv); fmaq(a + 8, wv.z, xv); fmaq(a + 12, wv.w, xv);
}
__device__ __forceinline__ void film4(float* a, float fj, float pj) {
  a[0] = fsin(__builtin_fmaf(fj, a[0], pj)); a[1] = fsin(__builtin_fmaf(fj, a[1], pj));
  a[2] = fsin(__builtin_fmaf(fj, a[2], pj)); a[3] = fsin(__builtin_fmaf(fj, a[3], pj));
}
__device__ __forceinline__ void spac(float* sp, float s, const float* a) {
  sp[0] = __builtin_fmaf(s, a[0], sp[0]); sp[1] = __builtin_fmaf(s, a[1], sp[1]);
  sp[2] = __builtin_fmaf(s, a[2], sp[2]); sp[3] = __builtin_fmaf(s, a[3], sp[3]);
}
__device__ __forceinline__ void bias_init(float* a, float4 bv) {
  a[0]=bv.x; a[1]=bv.x; a[2]=bv.x; a[3]=bv.x;
  a[4]=bv.y; a[5]=bv.y; a[6]=bv.y; a[7]=bv.y;
  a[8]=bv.z; a[9]=bv.z; a[10]=bv.z; a[11]=bv.z;
  a[12]=bv.w; a[13]=bv.w; a[14]=bv.w; a[15]=bv.w;
}
__device__ __forceinline__ void film_group(float* a, float4 f4, float4 p4) {
  f4.x = __builtin_fmaf(f4.x, 15.f, 30.f); f4.y = __builtin_fmaf(f4.y, 15.f, 30.f);
  f4.z = __builtin_fmaf(f4.z, 15.f, 30.f); f4.w = __builtin_fmaf(f4.w, 15.f, 30.f);
  film4(a + 0, f4.x, p4.x); film4(a + 4, f4.y, p4.y);
  film4(a + 8, f4.z, p4.z); film4(a + 12, f4.w, p4.w);
}

// acc layout: acc[g*16 + j*4 + i] -> output o = g*64 + tn*4 + j, point p = tm*4 + i
__device__ __forceinline__ void gemm_k(const float* __restrict__ Wt, const float* Xs,
                                       int r0, int K, int tm, int tn,
                                       float* __restrict__ acc)
{
  const float* xp = Xs + r0 * 64 + tm * 4;
  const float* wp = Wt + tn * 4;
  #pragma unroll 2
  for (int k = 0; k < K; ++k) {
    float4 xv = *(const float4*)(xp);
    float4 w0 = *(const float4*)(wp);
    float4 w1 = *(const float4*)(wp + 64);
    float4 w2 = *(const float4*)(wp + 128);
    float4 w3 = *(const float4*)(wp + 192);
    fmag(acc +  0, w0, xv);
    fmag(acc + 16, w1, xv);
    fmag(acc + 32, w2, xv);
    fmag(acc + 48, w3, xv);
    xp += 64; wp += 256;
  }
}

// ---------------- weight transpose into workspace ----------------
__global__ void transpose_w(const float* __restrict__ W1, const float* __restrict__ W2,
                            const float* __restrict__ Wcs, float* __restrict__ ws)
{
  int idx = blockIdx.x * 256 + threadIdx.x;
  if (idx < 16128) {                       // W1t[k][o] = W1[o][k], k<63
    int k = idx >> 8, o = idx & 255;
    ws[OFF_W1T + idx] = W1[o * 63 + k];
  } else if (idx < 16128 + 65536) {        // W2t[k][o] = W2[o][k]
    int t = idx - 16128;
    int k = t >> 8, o = t & 255;
    ws[OFF_W2T + t] = W2[o * 256 + k];
  } else if (idx < 16128 + 65536 + 72448) { // Wcst[k][o] = Wcs[o][k], k<283
    int t = idx - (16128 + 65536);
    int k = t >> 8, o = t & 255;
    ws[OFF_WCST + t] = Wcs[o * 283 + k];
  }
}

// ---------------- fused SIREN kernel ----------------
__global__ void __launch_bounds__(256, 2)
siren_fused(const float* __restrict__ input, const float* __restrict__ rdir,
            const float* __restrict__ sn,    const float* __restrict__ sc,
            const float* __restrict__ b1,    const float* __restrict__ b2,
            const float* __restrict__ Wf,    const float* __restrict__ bf,
            const float* __restrict__ bcs,   const float* __restrict__ Wcl,
            const float* __restrict__ bcl,   const float* __restrict__ ws,
            float* __restrict__ out)
{
  __shared__ float Xs[283 * 64];   // [row][pt]; rows 0..26 dir-embed, 27..282 pe/x1/x2

  const int tid = threadIdx.x;
  const int blk = blockIdx.x;
  const int b   = blk >> 10;            // 1024 blocks per batch
  const int pt0 = (blk & 1023) << 6;
  const int gbase = b * 65536 + pt0;    // global point base

  // ---- phase 0: positional embeds into LDS ----
  {
    const int pt = tid & 63, g = tid >> 6;
    const float* ip = input + (size_t)(gbase + pt) * 3;
    float x0 = ip[0] * SCALE_F, x1v = ip[1] * SCALE_F, x2v = ip[2] * SCALE_F;
    int qe = g * 16 + 16; if (qe > 63) qe = 63;
    for (int q = g * 16; q < qe; ++q) {
      float v;
      if (q < 3) v = (q == 0) ? x0 : (q == 1 ? x1v : x2v);
      else {
        int rr = q - 3, f = rr / 6, rem = rr - f * 6;
        int d = (rem < 3) ? rem : rem - 3;
        float xa = (d == 0) ? x0 : (d == 1 ? x1v : x2v);
        float arg = xa * (float)(1 << f);     // exact: power-of-2 frequency
        v = (rem < 3) ? fsin(arg) : fcos(arg);
      }
      Xs[(27 + q) * 64 + pt] = v;
    }
    const float* rp = rdir + (size_t)(gbase + pt) * 3;
    float r0v = rp[0], r1v = rp[1], r2v = rp[2];
    int q0 = g * 7, q1 = q0 + 7; if (q1 > 27) q1 = 27;
    for (int q = q0; q < q1; ++q) {
      float v;
      if (q < 3) v = (q == 0) ? r0v : (q == 1 ? r1v : r2v);
      else {
        int rr = q - 3, f = rr / 6, rem = rr - f * 6;
        int d = (rem < 3) ? rem : rem - 3;
        float ra = (d == 0) ? r0v : (d == 1 ? r1v : r2v);
        float arg = ra * (float)(1 << f);
        v = (rem < 3) ? fsin(arg) : fcos(arg);
      }
      Xs[q * 64 + pt] = v;
    }
  }
  __syncthreads();

  const int tn = tid & 15, tm = tid >> 4;
  float acc[64] __attribute__((aligned(16)));
  const float* snb = sn + b * 1024;
  const float* scb = sc + b * 512;

  // ---- layer 1: pe(63) -> x1(256) ----
  #pragma unroll
  for (int g = 0; g < 4; ++g)
    bias_init(acc + g * 16, *(const float4*)(b1 + g * 64 + tn * 4));
  gemm_k(ws + OFF_W1T, Xs, 27, 63, tm, tn, acc);
  #pragma unroll
  for (int g = 0; g < 4; ++g)
    film_group(acc + g * 16,
               *(const float4*)(snb + 0   + g * 64 + tn * 4),
               *(const float4*)(snb + 512 + g * 64 + tn * 4));
  __syncthreads();             // all waves done reading pe rows
  #pragma unroll
  for (int g = 0; g < 4; ++g)
    #pragma unroll
    for (int j = 0; j < 4; ++j) {
      int o = g * 64 + tn * 4 + j;
      *(float4*)(Xs + (27 + o) * 64 + tm * 4) = *(float4*)(acc + g * 16 + j * 4);
    }
  __syncthreads();

  // ---- layer 2: x1(256) -> x2(256) ----
  #pragma unroll
  for (int g = 0; g < 4; ++g)
    bias_init(acc + g * 16, *(const float4*)(b2 + g * 64 + tn * 4));
  gemm_k(ws + OFF_W2T, Xs, 27, 256, tm, tn, acc);
  #pragma unroll
  for (int g = 0; g < 4; ++g)
    film_group(acc + g * 16,
               *(const float4*)(snb + 256 + g * 64 + tn * 4),
               *(const float4*)(snb + 768 + g * 64 + tn * 4));
  // sigma partial from x2 while it is still in registers
  float sp[4] __attribute__((aligned(16))) = {0.f, 0.f, 0.f, 0.f};
  #pragma unroll
  for (int g = 0; g < 4; ++g) {
    float4 wf = *(const float4*)(Wf + g * 64 + tn * 4);
    float* a = acc + g * 16;
    spac(sp, wf.x, a + 0); spac(sp, wf.y, a + 4); spac(sp, wf.z, a + 8); spac(sp, wf.w, a + 12);
  }
  __syncthreads();             // all waves done reading x1 rows
  #pragma unroll
  for (int g = 0; g < 4; ++g)
    #pragma unroll
    for (int j = 0; j < 4; ++j) {
      int o = g * 64 + tn * 4 + j;
      *(float4*)(Xs + (27 + o) * 64 + tm * 4) = *(float4*)(acc + g * 16 + j * 4);
    }
  __syncthreads();

  // ---- layer 3 (color): [de(27); x2(256)] -> hc(256) ----
  #pragma unroll
  for (int g = 0; g < 4; ++g)
    bias_init(acc + g * 16, *(const float4*)(bcs + g * 64 + tn * 4));
  gemm_k(ws + OFF_WCST, Xs, 0, 283, tm, tn, acc);
  #pragma unroll
  for (int g = 0; g < 4; ++g)
    film_group(acc + g * 16,
               *(const float4*)(scb + 0   + g * 64 + tn * 4),
               *(const float4*)(scb + 256 + g * 64 + tn * 4));
  // rgb partials from hc in registers
  float rp0[4] __attribute__((aligned(16))) = {0.f,0.f,0.f,0.f};
  float rp1[4] __attribute__((aligned(16))) = {0.f,0.f,0.f,0.f};
  float rp2[4] __attribute__((aligned(16))) = {0.f,0.f,0.f,0.f};
  #pragma unroll
  for (int g = 0; g < 4; ++g) {
    float* a = acc + g * 16;
    float4 w0 = *(const float4*)(Wcl + 0 * 256 + g * 64 + tn * 4);
    float4 w1 = *(const float4*)(Wcl + 1 * 256 + g * 64 + tn * 4);
    float4 w2 = *(const float4*)(Wcl + 2 * 256 + g * 64 + tn * 4);
    spac(rp0, w0.x, a + 0); spac(rp0, w0.y, a + 4); spac(rp0, w0.z, a + 8); spac(rp0, w0.w, a + 12);
    spac(rp1, w1.x, a + 0); spac(rp1, w1.y, a + 4); spac(rp1, w1.z, a + 8); spac(rp1, w1.w, a + 12);
    spac(rp2, w2.x, a + 0); spac(rp2, w2.y, a + 4); spac(rp2, w2.z, a + 8); spac(rp2, w2.w, a + 12);
  }
  __syncthreads();             // all waves done reading de/x2 rows

  // ---- epilogue: reduce 16 thread-column partials per channel ----
  *(float4*)(Xs + (tn * 4 + 0) * 64 + tm * 4) = *(float4*)rp0;
  *(float4*)(Xs + (tn * 4 + 1) * 64 + tm * 4) = *(float4*)rp1;
  *(float4*)(Xs + (tn * 4 + 2) * 64 + tm * 4) = *(float4*)rp2;
  *(float4*)(Xs + (tn * 4 + 3) * 64 + tm * 4) = *(float4*)sp;
  __syncthreads();
  {
    const int pt = tid & 63, ch = tid >> 6;
    float s = 0.f;
    #pragma unroll
    for (int t = 0; t < 16; ++t) s += Xs[(t * 4 + ch) * 64 + pt];
    float bias = (ch == 0) ? bcl[0] : (ch == 1) ? bcl[1] : (ch == 2) ? bcl[2] : bf[0];
    out[(size_t)(gbase + pt) * 4 + ch] = s + bias;
  }
}

extern "C" void kernel_launch(void* const* d_in, const int* in_sizes, int n_in,
                              void* d_out, int out_size, void* d_ws, size_t ws_size,
                              hipStream_t stream) {
  const float* input = (const float*)d_in[0];
  const float* rdir  = (const float*)d_in[1];
  const float* sn    = (const float*)d_in[2];
  const float* sc    = (const float*)d_in[3];
  const float* W1    = (const float*)d_in[4];
  const float* b1    = (const float*)d_in[5];
  const float* W2    = (const float*)d_in[6];
  const float* b2    = (const float*)d_in[7];
  const float* Wf    = (const float*)d_in[8];
  const float* bf    = (const float*)d_in[9];
  const float* Wcs   = (const float*)d_in[10];
  const float* bcs   = (const float*)d_in[11];
  const float* Wcl   = (const float*)d_in[12];
  const float* bcl   = (const float*)d_in[13];
  float* ws  = (float*)d_ws;
  float* out = (float*)d_out;

  transpose_w<<<602, 256, 0, stream>>>(W1, W2, Wcs, ws);
  siren_fused<<<4096, 256, 0, stream>>>(input, rdir, sn, sc, b1, b2, Wf, bf,
                                        bcs, Wcl, bcl, ws, out);
}

// Round 3
// 333.655 us; speedup vs baseline: 3.6421x; 3.6421x over previous
//
#include <hip/hip_runtime.h>

// ShallowSIRENWithPosEmb — bf16-split MFMA version.
// B=4, N=65536, H=256. 128 points/block, 512 threads (8 waves: 4 pt-tiles x 2 out-halves).
// Each GEMM: (Xh+Xl)(Wh+Wl) ~= Xh*Wh + Xl*Wh + Xh*Wl via 3x mfma_f32_32x32x16_bf16, fp32 acc.
// W pre-split into hi/lo bf16 planes in MFMA-slab order (prep_w) -> linear LDS staging.
// A=W (row=out), B=X (col=pt): D[out][pt]; C/D layout col=lane&31, row=(reg&3)+8*(reg>>2)+4*(lane>>5).

#define SCALE_F 8.333333333333334f   // 2/0.24

typedef __attribute__((ext_vector_type(8)))  short sh8;     // 8 bf16 (4 VGPR)
typedef __attribute__((ext_vector_type(16))) float f32x16;  // MFMA acc

// ---- accurate sin/cos: Cody-Waite reduction to revolutions + v_sin/v_cos ----
__device__ __forceinline__ float redrev(float x) {
  const float chi = 0.15915494309189535f;
  const float clo = 6.4206383e-09f;
  float n = rintf(x * chi);
  float d = __builtin_fmaf(x, chi, -n);
  return __builtin_fmaf(x, clo, d);
}
__device__ __forceinline__ float fsin(float x) { return __builtin_amdgcn_sinf(redrev(x)); }
__device__ __forceinline__ float fcos(float x) { return __builtin_amdgcn_cosf(redrev(x)); }

// ---- bf16 helpers (rne) ----
__device__ __forceinline__ unsigned short bfh(float v) {
  unsigned u = __float_as_uint(v);
  return (unsigned short)((u + 0x7fffu + ((u >> 16) & 1u)) >> 16);
}
__device__ __forceinline__ float bf2f(unsigned short h) {
  return __uint_as_float(((unsigned)h) << 16);
}

// ---- weight prep: split W into hi/lo bf16 planes, permuted into MFMA slab order ----
// slab (per kstep, 8192 ushort = 16KB): [hi:4096][lo:4096]; within: [ot:8][kh:2][o5:32][j:8]
// layers: L1 base 0 (4 slabs), L2 base 32768 (16), L3 base 163840 (18). total 311296 ushort.
__global__ void prep_w(const float* __restrict__ W1, const float* __restrict__ W2,
                       const float* __restrict__ Wcs, unsigned short* __restrict__ wsu)
{
  int t = blockIdx.x * 256 + threadIdx.x;
  if (t >= 155648) return;
  int L, pos, base;
  if (t < 16384)      { L = 0; pos = t;         base = 0; }
  else if (t < 81920) { L = 1; pos = t - 16384; base = 32768; }
  else                { L = 2; pos = t - 81920; base = 163840; }
  int kstep = pos >> 12, r = pos & 4095;
  int ot = (r >> 9) & 7, kh = (r >> 8) & 1, o5 = (r >> 3) & 31, j = r & 7;
  int o = ot * 32 + o5, k = kstep * 16 + kh * 8 + j;
  float wv = 0.f;
  if (L == 0)      { if (k < 63) wv = W1[o * 63 + k]; }
  else if (L == 1) { wv = W2[o * 256 + k]; }
  else             { if (k < 27) wv = Wcs[o * 283 + k];
                     else if (k >= 32) wv = Wcs[o * 283 + k - 5]; }   // [de27|pad5|x256]
  unsigned short h = bfh(wv);
  unsigned short lo = bfh(wv - bf2f(h));
  wsu[base + kstep * 8192 + r] = h;
  wsu[base + kstep * 8192 + 4096 + r] = lo;
}

// ---- one layer's MFMA loop. NREG leading ksteps take B from registers. ----
template <int NREG>
__device__ __forceinline__ void mfma_layer(
    const unsigned short* __restrict__ prep, int nk,
    const uint4* rBh, const uint4* rBl,
    unsigned short* lW, const unsigned short* lX,
    int myp, int lh, int l31, int ow, int tid, f32x16* acc)
{
  { // prologue: stage slab 0
    const float4* s = (const float4*)prep;
    ((float4*)lW)[tid] = s[tid];
    ((float4*)lW)[tid + 512] = s[tid + 512];
  }
  __syncthreads();
  #pragma unroll 1
  for (int ks = 0; ks < nk; ++ks) {
    float4 pf0, pf1;
    const bool pre = (ks + 1) < nk;
    if (pre) {  // register prefetch of next slab (hidden under MFMAs)
      const float4* s = (const float4*)(prep + (size_t)(ks + 1) * 8192);
      pf0 = s[tid]; pf1 = s[tid + 512];
    }
    sh8 Bh, Bl;
    if (NREG > 0 && ks < NREG) {
      uint4 h = {0,0,0,0}, l = {0,0,0,0};
      #pragma unroll
      for (int rr = 0; rr < NREG; ++rr) if (ks == rr) { h = rBh[rr]; l = rBl[rr]; }
      Bh = __builtin_bit_cast(sh8, h); Bl = __builtin_bit_cast(sh8, l);
    } else {
      const int c0 = (((ks - NREG) * 16 + lh * 8) ^ ((myp & 15) << 3));
      Bh = *(const sh8*)&lX[myp * 256 + c0];
      Bl = *(const sh8*)&lX[32768 + myp * 256 + c0];
    }
    #pragma unroll
    for (int o = 0; o < 4; ++o) {
      const int wb = (ow * 4 + o) * 512 + lh * 256 + l31 * 8;
      sh8 Ah = *(const sh8*)&lW[wb];
      sh8 Al = *(const sh8*)&lW[4096 + wb];
      acc[o] = __builtin_amdgcn_mfma_f32_32x32x16_bf16(Ah, Bh, acc[o], 0, 0, 0);
      acc[o] = __builtin_amdgcn_mfma_f32_32x32x16_bf16(Al, Bh, acc[o], 0, 0, 0);
      acc[o] = __builtin_amdgcn_mfma_f32_32x32x16_bf16(Ah, Bl, acc[o], 0, 0, 0);
    }
    __syncthreads();                 // everyone done reading slab ks
    if (pre) { ((float4*)lW)[tid] = pf0; ((float4*)lW)[tid + 512] = pf1; }
    __syncthreads();                 // slab ks+1 visible
  }
}

// film a group of 4 consecutive outs
__device__ __forceinline__ float4 film_g(float4 fr, float4 ph, float a0, float a1, float a2, float a3) {
  float4 r;
  r.x = fsin(__builtin_fmaf(__builtin_fmaf(fr.x, 15.f, 30.f), a0, ph.x));
  r.y = fsin(__builtin_fmaf(__builtin_fmaf(fr.y, 15.f, 30.f), a1, ph.y));
  r.z = fsin(__builtin_fmaf(__builtin_fmaf(fr.z, 15.f, 30.f), a2, ph.z));
  r.w = fsin(__builtin_fmaf(__builtin_fmaf(fr.w, 15.f, 30.f), a3, ph.w));
  return r;
}
// split-store 4 values to X hi/lo planes (8B packed writes)
__device__ __forceinline__ void store_g(unsigned short* lX, int idx, float4 v) {
  unsigned short h0 = bfh(v.x), h1 = bfh(v.y), h2 = bfh(v.z), h3 = bfh(v.w);
  *(uint2*)&lX[idx] = make_uint2((unsigned)h0 | ((unsigned)h1 << 16),
                                 (unsigned)h2 | ((unsigned)h3 << 16));
  unsigned short l0 = bfh(v.x - bf2f(h0)), l1 = bfh(v.y - bf2f(h1));
  unsigned short l2 = bfh(v.z - bf2f(h2)), l3 = bfh(v.w - bf2f(h3));
  *(uint2*)&lX[32768 + idx] = make_uint2((unsigned)l0 | ((unsigned)l1 << 16),
                                         (unsigned)l2 | ((unsigned)l3 << 16));
}

__global__ void __launch_bounds__(512, 2)
siren_mfma(const float* __restrict__ input, const float* __restrict__ rdir,
           const float* __restrict__ sn, const float* __restrict__ sc,
           const float* __restrict__ b1, const float* __restrict__ b2,
           const float* __restrict__ Wf, const float* __restrict__ bfp,
           const float* __restrict__ bcs, const float* __restrict__ Wcl,
           const float* __restrict__ bcl, const unsigned short* __restrict__ wsu,
           float* __restrict__ out)
{
  __shared__ __align__(16) unsigned short lW[8192];    // 16KB W slab
  __shared__ __align__(16) unsigned short lX[65536];   // 128KB: X hi [0..32767], lo [32768..]
  __shared__ float lP[8][32][4];                       // per-wave output partials

  const int tid = threadIdx.x;
  const int w = tid >> 6, l = tid & 63;
  const int pw = w >> 1, ow = w & 1;                   // pt-tile, out-half
  const int l31 = l & 31, lh = l >> 5;
  const int gpt0 = blockIdx.x * 128;
  const int b = gpt0 >> 16;
  const int myp = pw * 32 + l31;                       // point within block (B col / D col)
  const int gp = gpt0 + myp;
  const float* snb = sn + b * 1024;
  const float* scb = sc + b * 512;
  const int swz = (myp & 15) << 3;

  // ---- in-register embed B-fragments ----
  uint4 peh[4], pel[4], deh[2], del[2];
  {
    const float* ip = input + (size_t)gp * 3;
    float x0 = ip[0] * SCALE_F, x1 = ip[1] * SCALE_F, x2 = ip[2] * SCALE_F;
    const float* rp = rdir + (size_t)gp * 3;
    float r0 = rp[0], r1 = rp[1], r2 = rp[2];
    #pragma unroll
    for (int ks = 0; ks < 4; ++ks) {
      unsigned short hh[8], ll[8];
      #pragma unroll
      for (int j = 0; j < 8; ++j) {
        int k = ks * 16 + lh * 8 + j;
        float val;
        if (k >= 63) val = 0.f;
        else if (k < 3) val = (k == 0) ? x0 : (k == 1 ? x1 : x2);
        else {
          int rr = k - 3, f = rr / 6, rem = rr - f * 6;
          int d = (rem < 3) ? rem : rem - 3;
          float xa = (d == 0) ? x0 : (d == 1 ? x1 : x2);
          float arg = xa * (float)(1 << f);
          val = (rem < 3) ? fsin(arg) : fcos(arg);
        }
        hh[j] = bfh(val); ll[j] = bfh(val - bf2f(hh[j]));
      }
      peh[ks] = make_uint4((unsigned)hh[0] | ((unsigned)hh[1] << 16), (unsigned)hh[2] | ((unsigned)hh[3] << 16),
                           (unsigned)hh[4] | ((unsigned)hh[5] << 16), (unsigned)hh[6] | ((unsigned)hh[7] << 16));
      pel[ks] = make_uint4((unsigned)ll[0] | ((unsigned)ll[1] << 16), (unsigned)ll[2] | ((unsigned)ll[3] << 16),
                           (unsigned)ll[4] | ((unsigned)ll[5] << 16), (unsigned)ll[6] | ((unsigned)ll[7] << 16));
    }
    #pragma unroll
    for (int ks = 0; ks < 2; ++ks) {
      unsigned short hh[8], ll[8];
      #pragma unroll
      for (int j = 0; j < 8; ++j) {
        int k = ks * 16 + lh * 8 + j;
        float val;
        if (k >= 27) val = 0.f;
        else if (k < 3) val = (k == 0) ? r0 : (k == 1 ? r1 : r2);
        else {
          int rr = k - 3, f = rr / 6, rem = rr - f * 6;
          int d = (rem < 3) ? rem : rem - 3;
          float ra = (d == 0) ? r0 : (d == 1 ? r1 : r2);
          float arg = ra * (float)(1 << f);
          val = (rem < 3) ? fsin(arg) : fcos(arg);
        }
        hh[j] = bfh(val); ll[j] = bfh(val - bf2f(hh[j]));
      }
      deh[ks] = make_uint4((unsigned)hh[0] | ((unsigned)hh[1] << 16), (unsigned)hh[2] | ((unsigned)hh[3] << 16),
                           (unsigned)hh[4] | ((unsigned)hh[5] << 16), (unsigned)hh[6] | ((unsigned)hh[7] << 16));
      del[ks] = make_uint4((unsigned)ll[0] | ((unsigned)ll[1] << 16), (unsigned)ll[2] | ((unsigned)ll[3] << 16),
                           (unsigned)ll[4] | ((unsigned)ll[5] << 16), (unsigned)ll[6] | ((unsigned)ll[7] << 16));
    }
  }

  f32x16 acc[4];

  // ================= layer 1: pe(64) -> x1(256) =================
  #pragma unroll
  for (int o = 0; o < 4; ++o) {
    #pragma unroll
    for (int g = 0; g < 4; ++g) {
      int ob = (ow * 4 + o) * 32 + g * 8 + lh * 4;
      float4 bv = *(const float4*)&b1[ob];
      acc[o][g * 4 + 0] = bv.x; acc[o][g * 4 + 1] = bv.y;
      acc[o][g * 4 + 2] = bv.z; acc[o][g * 4 + 3] = bv.w;
    }
  }
  mfma_layer<4>(wsu + 0, 4, peh, pel, lW, lX, myp, lh, l31, ow, tid, acc);
  #pragma unroll
  for (int o = 0; o < 4; ++o) {
    #pragma unroll
    for (int g = 0; g < 4; ++g) {
      int ob = (ow * 4 + o) * 32 + g * 8 + lh * 4;
      float4 fr = *(const float4*)&snb[ob];
      float4 ph = *(const float4*)&snb[512 + ob];
      float4 vv = film_g(fr, ph, acc[o][g*4+0], acc[o][g*4+1], acc[o][g*4+2], acc[o][g*4+3]);
      store_g(lX, myp * 256 + (ob ^ swz), vv);
    }
  }

  // ================= layer 2: x1(256) -> x2(256), sigma =================
  #pragma unroll
  for (int o = 0; o < 4; ++o) {
    #pragma unroll
    for (int g = 0; g < 4; ++g) {
      int ob = (ow * 4 + o) * 32 + g * 8 + lh * 4;
      float4 bv = *(const float4*)&b2[ob];
      acc[o][g * 4 + 0] = bv.x; acc[o][g * 4 + 1] = bv.y;
      acc[o][g * 4 + 2] = bv.z; acc[o][g * 4 + 3] = bv.w;
    }
  }
  mfma_layer<0>(wsu + 32768, 16, nullptr, nullptr, lW, lX, myp, lh, l31, ow, tid, acc);
  float sp = 0.f;
  #pragma unroll
  for (int o = 0; o < 4; ++o) {
    #pragma unroll
    for (int g = 0; g < 4; ++g) {
      int ob = (ow * 4 + o) * 32 + g * 8 + lh * 4;
      float4 fr = *(const float4*)&snb[256 + ob];
      float4 ph = *(const float4*)&snb[768 + ob];
      float4 vv = film_g(fr, ph, acc[o][g*4+0], acc[o][g*4+1], acc[o][g*4+2], acc[o][g*4+3]);
      float4 wf = *(const float4*)&Wf[ob];
      sp = __builtin_fmaf(wf.x, vv.x, sp); sp = __builtin_fmaf(wf.y, vv.y, sp);
      sp = __builtin_fmaf(wf.z, vv.z, sp); sp = __builtin_fmaf(wf.w, vv.w, sp);
      store_g(lX, myp * 256 + (ob ^ swz), vv);
    }
  }
  sp += __shfl_xor(sp, 32);
  lP[w][l31][3] = sp;

  // ================= layer 3: [de(32)|x2(256)] -> hc(256), rgb =================
  #pragma unroll
  for (int o = 0; o < 4; ++o) {
    #pragma unroll
    for (int g = 0; g < 4; ++g) {
      int ob = (ow * 4 + o) * 32 + g * 8 + lh * 4;
      float4 bv = *(const float4*)&bcs[ob];
      acc[o][g * 4 + 0] = bv.x; acc[o][g * 4 + 1] = bv.y;
      acc[o][g * 4 + 2] = bv.z; acc[o][g * 4 + 3] = bv.w;
    }
  }
  mfma_layer<2>(wsu + 163840, 18, deh, del, lW, lX, myp, lh, l31, ow, tid, acc);
  float q0 = 0.f, q1 = 0.f, q2 = 0.f;
  #pragma unroll
  for (int o = 0; o < 4; ++o) {
    #pragma unroll
    for (int g = 0; g < 4; ++g) {
      int ob = (ow * 4 + o) * 32 + g * 8 + lh * 4;
      float4 fr = *(const float4*)&scb[ob];
      float4 ph = *(const float4*)&scb[256 + ob];
      float4 vv = film_g(fr, ph, acc[o][g*4+0], acc[o][g*4+1], acc[o][g*4+2], acc[o][g*4+3]);
      float4 w0 = *(const float4*)&Wcl[ob];
      float4 w1 = *(const float4*)&Wcl[256 + ob];
      float4 w2 = *(const float4*)&Wcl[512 + ob];
      q0 = __builtin_fmaf(w0.x, vv.x, q0); q0 = __builtin_fmaf(w0.y, vv.y, q0);
      q0 = __builtin_fmaf(w0.z, vv.z, q0); q0 = __builtin_fmaf(w0.w, vv.w, q0);
      q1 = __builtin_fmaf(w1.x, vv.x, q1); q1 = __builtin_fmaf(w1.y, vv.y, q1);
      q1 = __builtin_fmaf(w1.z, vv.z, q1); q1 = __builtin_fmaf(w1.w, vv.w, q1);
      q2 = __builtin_fmaf(w2.x, vv.x, q2); q2 = __builtin_fmaf(w2.y, vv.y, q2);
      q2 = __builtin_fmaf(w2.z, vv.z, q2); q2 = __builtin_fmaf(w2.w, vv.w, q2);
    }
  }
  q0 += __shfl_xor(q0, 32); q1 += __shfl_xor(q1, 32); q2 += __shfl_xor(q2, 32);
  lP[w][l31][0] = q0; lP[w][l31][1] = q1; lP[w][l31][2] = q2;
  __syncthreads();

  // ---- epilogue: combine the 2 out-half waves per pt-tile, add biases, store ----
  {
    int pt = tid >> 2, ch = tid & 3, pv = pt >> 5;
    float v = lP[pv * 2][pt & 31][ch] + lP[pv * 2 + 1][pt & 31][ch];
    v += (ch == 3) ? bfp[0] : bcl[ch];
    out[(size_t)gpt0 * 4 + tid] = v;
  }
}

extern "C" void kernel_launch(void* const* d_in, const int* in_sizes, int n_in,
                              void* d_out, int out_size, void* d_ws, size_t ws_size,
                              hipStream_t stream) {
  const float* input = (const float*)d_in[0];
  const float* rdir  = (const float*)d_in[1];
  const float* sn    = (const float*)d_in[2];
  const float* sc    = (const float*)d_in[3];
  const float* W1    = (const float*)d_in[4];
  const float* b1    = (const float*)d_in[5];
  const float* W2    = (const float*)d_in[6];
  const float* b2    = (const float*)d_in[7];
  const float* Wf    = (const float*)d_in[8];
  const float* bf    = (const float*)d_in[9];
  const float* Wcs   = (const float*)d_in[10];
  const float* bcs   = (const float*)d_in[11];
  const float* Wcl   = (const float*)d_in[12];
  const float* bcl   = (const float*)d_in[13];
  unsigned short* wsu = (unsigned short*)d_ws;
  float* out = (float*)d_out;

  prep_w<<<608, 256, 0, stream>>>(W1, W2, Wcs, wsu);
  siren_mfma<<<2048, 512, 0, stream>>>(input, rdir, sn, sc, b1, b2, Wf, bf,
                                       bcs, Wcl, bcl, wsu, out);
}